// Round 12
// baseline (196.527 us; speedup 1.0000x reference)
//
#include <hip/hip_runtime.h>

typedef unsigned short u16;
typedef unsigned int   u32;
typedef __attribute__((ext_vector_type(4))) float f32x4;
typedef __attribute__((ext_vector_type(8))) short bf16x8;
typedef __attribute__((ext_vector_type(8))) unsigned short u16x8;
typedef __attribute__((ext_vector_type(4))) unsigned short u16x4;

#define MROWS 4096
#define DDIM  1024
#define SEGE  4194304   // 4096*1024 u16 elements per hi/lo segment

__device__ __forceinline__ u16 f2bf(float f) {
  u32 u = __float_as_uint(f);
  return (u16)((u + 0x7FFFu + ((u >> 16) & 1u)) >> 16);   // RNE
}
__device__ __forceinline__ float bf2f(u16 h) { return __uint_as_float(((u32)h) << 16); }

// ---------- JAX partitionable threefry2x32, key(42): bits(n) = o0^o1 ----------
__device__ __forceinline__ u32 rotl32(u32 x, int r) { return (x << r) | (x >> (32 - r)); }
__device__ __forceinline__ u32 threefry_bits(u32 n) {
  const u32 K0 = 0u, K1 = 42u, K2 = 0x1BD11BDAu ^ 0u ^ 42u;
  u32 x0 = K0;
  u32 x1 = n + K1;
#define TF4(a,b,c,d) \
  x0 += x1; x1 = rotl32(x1, a); x1 ^= x0; \
  x0 += x1; x1 = rotl32(x1, b); x1 ^= x0; \
  x0 += x1; x1 = rotl32(x1, c); x1 ^= x0; \
  x0 += x1; x1 = rotl32(x1, d); x1 ^= x0;
  TF4(13,15,26,6);  x0 += K1; x1 += K2 + 1u;
  TF4(17,29,16,24); x0 += K2; x1 += K0 + 2u;
  TF4(13,15,26,6);  x0 += K0; x1 += K1 + 3u;
  TF4(17,29,16,24); x0 += K1; x1 += K2 + 4u;
  TF4(13,15,26,6);  x0 += K2; x1 += K0 + 5u;
#undef TF4
  return x0 ^ x1;
}

// ============ merged prep: expand x1 -> Ah|Al ; x2 -> Bh|Bl + VT ============
// blocks [0,2048): expandA ; blocks [2048,3072): castB+transpose
__global__ __launch_bounds__(256)
void prep(const float4* __restrict__ x1, u16* __restrict__ XA,
          const float* __restrict__ x2, u16* __restrict__ XB, u16* __restrict__ VT) {
  __shared__ float tile[64][65];
  const int tid = threadIdx.x;
  const int b = blockIdx.x;
  if (b < 2048) {
    int t = b * 256 + tid;                       // 524288 threads, 8 floats each
    float4 v0 = x1[(size_t)t * 2], v1 = x1[(size_t)t * 2 + 1];
    float vv[8] = {v0.x*4.f, v0.y*4.f, v0.z*4.f, v0.w*4.f,
                   v1.x*4.f, v1.y*4.f, v1.z*4.f, v1.w*4.f};
    u16x8 hwv, lwv;
#pragma unroll
    for (int j = 0; j < 8; ++j) {
      u16 h = f2bf(vv[j]);
      hwv[j] = h;
      lwv[j] = f2bf(vv[j] - bf2f(h));            // Sterbenz-exact residual, RNE
    }
    *(u16x8*)(XA + (size_t)t * 8)        = hwv;
    *(u16x8*)(XA + SEGE + (size_t)t * 8) = lwv;
    return;
  }
  const int bb = b - 2048;
  const int dt = bb & 15;    // 16 D-tiles
  const int kt = bb >> 4;    // 64 K-tiles
#pragma unroll
  for (int it = 0; it < 16; ++it) {
    int lin = it * 256 + tid;
    int r = lin >> 6, c = lin & 63;
    tile[r][c] = x2[(size_t)(kt*64 + r) * DDIM + dt*64 + c];
  }
  __syncthreads();
#pragma unroll
  for (int itr = 0; itr < 2; ++itr) {
    int r  = (tid >> 3) + itr * 32;
    int c0 = (tid & 7) * 8;
    u16x8 hwv, lwv;
#pragma unroll
    for (int j = 0; j < 8; ++j) {
      float v = tile[r][c0 + j];
      u16 h = f2bf(v);
      hwv[j] = h;
      lwv[j] = f2bf(v - bf2f(h));
    }
    size_t off = (size_t)(kt*64 + r) * DDIM + dt*64 + c0;
    *(u16x8*)(XB + off)        = hwv;
    *(u16x8*)(XB + SEGE + off) = lwv;
  }
  // VT[d][k] = bf16(x2[k][d]); 16B per thread store
#pragma unroll
  for (int it = 0; it < 2; ++it) {
    int dr  = (tid >> 3) + it * 32;
    int kc0 = (tid & 7) * 8;
    u16x8 wv;
#pragma unroll
    for (int j = 0; j < 8; ++j) wv[j] = f2bf(tile[kc0 + j][dr]);
    *(u16x8*)(VT + (size_t)(dt*64 + dr) * MROWS + kt*64 + kc0) = wv;
  }
}

// ============ 256x256 pipelined 8-phase GEMM body (round-7 engine) ============
// SEG3: A = [Ah|Al], B = [Bh|Bl] panels of K=1024. INTERLEAVED k-tile map:
//   col = tau/3, seg = tau%3 ; seg 0: Ah*Bh, 1: Ah*Bl, 2: Al*Bh.
// C-writes are NON-TEMPORAL: S/PT are stream-once data; keep panels in L2.
__device__ __forceinline__ void gload16(const u16* g, u16* l) {
  __builtin_amdgcn_global_load_lds(
      (const __attribute__((address_space(1))) void*)g,
      (__attribute__((address_space(3))) void*)l, 16, 0, 0);
}

#define BARRIER() do { asm volatile("" ::: "memory"); __builtin_amdgcn_s_barrier(); \
                       asm volatile("" ::: "memory"); } while (0)
#define VMCNT(N)  asm volatile("s_waitcnt vmcnt(" #N ")" ::: "memory")
#define PRIO1()   __builtin_amdgcn_s_setprio(1)
#define PRIO0()   __builtin_amdgcn_s_setprio(0)

__device__ __forceinline__ void mma_quad(f32x4 (&acc)[8][4], const bf16x8 (&aF)[4][2],
                                         const bf16x8 (&bF)[2][2], int MH, int NH) {
#pragma unroll
  for (int kx = 0; kx < 2; ++kx)
#pragma unroll
    for (int m = 0; m < 4; ++m)
#pragma unroll
      for (int n = 0; n < 2; ++n)
        acc[MH*4+m][NH*2+n] = __builtin_amdgcn_mfma_f32_16x16x32_bf16(
            aF[m][kx], bF[n][kx], acc[MH*4+m][NH*2+n], 0, 0, 0);
}

// LDS u16 layout: A(d,h) = (d*2+h)*8192 ; B(d,h) = 32768 + (d*2+h)*8192
template <bool OUT16, bool REMAP, bool SEG3>
__device__ __forceinline__ void gemm_body(const u16* __restrict__ A,
                                          const u16* __restrict__ Bt,
                                          void* __restrict__ Cv,
                                          int M, int N, int K, int ntpc) {
  __shared__ u16 smem[65536];   // 128 KiB
  const int tid = threadIdx.x;
  const int lane = tid & 63;
  const int w = tid >> 6;
  const int wr = w >> 2;          // 0..1
  const int wc = w & 3;           // 0..3
  const int fr = lane & 15;
  const int hi = lane >> 4;

  int bxi, byi;
  if (REMAP) {  // G2 (grid 4x16xZ): 2 by-rows per XCD -> L2-resident k-window
    const int id0 = blockIdx.y * gridDim.x + blockIdx.x;  // 0..63
    const int c = id0 & 7, j = id0 >> 3;
    bxi = j >> 1;
    byi = c * 2 + (j & 1);
  } else {
    bxi = blockIdx.x; byi = blockIdx.y;
  }

  const long bm = (long)byi * 256;
  const long bn = (long)bxi * 256;
  const size_t kcol0 = (size_t)blockIdx.z * ntpc * 64;

  const int srow = tid >> 3;
  const int scol = (((tid & 7) ^ (srow & 7)) << 3);
  const u16* Abase = A  + (size_t)(bm + srow) * K + kcol0 + scol;
  const u16* Bbase = Bt + (size_t)(bn + srow) * K + kcol0 + scol;

  // interleaved segment map (SEG3), uniform per block
#define SCOL(TAU) ((TAU) / 3)
#define SSEG(TAU) ((TAU) - 3 * SCOL(TAU))
#define ASEG(TAU) (SEG3 ? (Abase + (SSEG(TAU) == 2 ? (size_t)SEGE : (size_t)0) \
                                 + (size_t)SCOL(TAU)*64) \
                        : (Abase + (size_t)(TAU)*64))
#define BSEG(TAU) (SEG3 ? (Bbase + (SSEG(TAU) == 1 ? (size_t)SEGE : (size_t)0) \
                                 + (size_t)SCOL(TAU)*64) \
                        : (Bbase + (size_t)(TAU)*64))

  const int csw0 = ((hi)     ^ (fr & 7)) << 3;
  const int csw1 = ((4 + hi) ^ (fr & 7)) << 3;
  const int arow = (wr*16 + fr) * 64;
  const int brow = (wc*16 + fr) * 64;

  // RD_A2: 2 M-frags (4 ds_read_b128); RD_B: both N-frags (4)
#define RD_A2(dst, D, H, M0) do { \
    const u16* _p = smem + ((D)*2+(H))*8192 + arow + (M0)*2048; \
    dst[M0][0]   = *(const bf16x8*)(_p + csw0); \
    dst[M0][1]   = *(const bf16x8*)(_p + csw1); \
    dst[M0+1][0] = *(const bf16x8*)(_p + 2048 + csw0); \
    dst[M0+1][1] = *(const bf16x8*)(_p + 2048 + csw1); } while (0)
#define RD_B(dst, D, H) do { \
    const u16* _p = smem + 32768 + ((D)*2+(H))*8192 + brow; \
    dst[0][0] = *(const bf16x8*)(_p + csw0); \
    dst[0][1] = *(const bf16x8*)(_p + csw1); \
    dst[1][0] = *(const bf16x8*)(_p + 4096 + csw0); \
    dst[1][1] = *(const bf16x8*)(_p + 4096 + csw1); } while (0)

  f32x4 acc[8][4];
#pragma unroll
  for (int m = 0; m < 8; ++m)
#pragma unroll
    for (int n = 0; n < 4; ++n) acc[m][n] = (f32x4){0.f, 0.f, 0.f, 0.f};
  bf16x8 a0[4][2], a1[4][2], b0[2][2], b1[2][2];

#define STAGE_A(TAU,H,D) do { \
    const u16* _s = ASEG(TAU) + (size_t)(H)*128*K; \
    u16* _d = smem + ((D)*2+(H))*8192 + tid*8; \
    gload16(_s, _d); gload16(_s + (size_t)64*K, _d + 4096); } while (0)
#define STAGE_B(TAU,H,D) do { \
    const u16* _s = BSEG(TAU) + (size_t)(H)*128*K; \
    u16* _d = smem + 32768 + ((D)*2+(H))*8192 + tid*8; \
    gload16(_s, _d); gload16(_s + (size_t)64*K, _d + 4096); } while (0)

  // ---- prologue: tile0 landed; tile1's 8 loads left in flight (FIFO invariant) ----
  STAGE_A(0,0,0); STAGE_B(0,0,0);
  STAGE_B(0,1,0); STAGE_A(0,1,0);
  VMCNT(0); BARRIER();
  RD_A2(a0,0,0,0); RD_A2(a0,0,0,2); RD_B(b0,0,0);   // regs for p1
  STAGE_A(1,0,1); STAGE_B(1,0,1);                   // A0,B0(1)
  STAGE_B(1,1,1);                                   // B1(1)
  STAGE_A(1,1,1);                                   // A1(1)
  BARRIER();                                        // 8 outstanding at loop-top

  const int nt = ntpc;
  for (int T = 0; T < nt; T += 2) {
    const int t2 = (T + 2 < nt) ? T + 2 : nt - 1;   // tail: idempotent re-stage
    const int t3 = (T + 3 < nt) ? T + 3 : nt - 1;

    // p1: MFMA Q00(T)[a0,b0]; read b1(T), a1[01](T)           (8 reads)
    RD_B(b1, 0, 1); RD_A2(a1, 0, 1, 0);
    PRIO1(); mma_quad(acc, a0, b0, 0, 0); PRIO0();
    BARRIER();
    // p2: MFMA Q01(T)[a0,b1]; read a1[23](T); stage A0,B0(T+2) (4 reads)
    RD_A2(a1, 0, 1, 2);
    STAGE_A(t2, 0, 0); STAGE_B(t2, 0, 0);
    PRIO1(); mma_quad(acc, a0, b1, 0, 1); PRIO0();
    VMCNT(10); BARRIER();                 // drains A0(T+1) for p3
    // p3: MFMA Q10(T)[a1,b0]; read a0[01](T+1); stage B1(T+2)  (4 reads)
    RD_A2(a0, 1, 0, 0);
    STAGE_B(t2, 1, 0);
    PRIO1(); mma_quad(acc, a1, b0, 1, 0); PRIO0();
    VMCNT(10); BARRIER();                 // drains B0(T+1) for p4
    // p4: MFMA Q11(T)[a1,b1]; read a0[23](T+1), b0(T+1); stage A1(T+2) (8 reads)
    RD_A2(a0, 1, 0, 2); RD_B(b0, 1, 0);
    STAGE_A(t2, 1, 0);
    PRIO1(); mma_quad(acc, a1, b1, 1, 1); PRIO0();
    VMCNT(8); BARRIER();                  // drains B1(T+1), A1(T+1) for p5
    // p5: MFMA Q00(T+1)[a0,b0]; read b1(T+1), a1[01](T+1)      (8 reads)
    RD_B(b1, 1, 1); RD_A2(a1, 1, 1, 0);
    PRIO1(); mma_quad(acc, a0, b0, 0, 0); PRIO0();
    BARRIER();
    // p6: MFMA Q01(T+1)[a0,b1]; read a1[23](T+1); stage A0,B0(T+3) (4 reads)
    RD_A2(a1, 1, 1, 2);
    STAGE_A(t3, 0, 1); STAGE_B(t3, 0, 1);
    PRIO1(); mma_quad(acc, a0, b1, 0, 1); PRIO0();
    VMCNT(10); BARRIER();                 // drains A0(T+2) for p7
    // p7: MFMA Q10(T+1)[a1,b0]; read a0[01](T+2); stage B1(T+3) (4 reads)
    RD_A2(a0, 0, 0, 0);
    STAGE_B(t3, 1, 1);
    PRIO1(); mma_quad(acc, a1, b0, 1, 0); PRIO0();
    VMCNT(10); BARRIER();                 // drains B0(T+2) for p8
    // p8: MFMA Q11(T+1)[a1,b1]; read a0[23](T+2), b0(T+2); stage A1(T+3) (8 reads)
    RD_A2(a0, 0, 0, 2); RD_B(b0, 0, 0);
    STAGE_A(t3, 1, 1);
    PRIO1(); mma_quad(acc, a1, b1, 1, 1); PRIO0();
    VMCNT(8); BARRIER();                  // drains B1(T+2), A1(T+2) for next p1
  }
#undef STAGE_A
#undef STAGE_B
#undef RD_A2
#undef RD_B
#undef ASEG
#undef BSEG
#undef SCOL
#undef SSEG

  // epilogue: C/D layout col=lane&15, row=(lane>>4)*4+reg  [verified m89/m91]
  // NON-TEMPORAL stores: S/PT are written once, read once -> don't evict panels.
#pragma unroll
  for (int m = 0; m < 8; ++m)
#pragma unroll
    for (int n = 0; n < 4; ++n) {
      size_t row0 = (size_t)(bm + m*32 + wr*16 + hi*4);
      size_t col  = (size_t)(bn + n*64 + wc*16 + fr);
#pragma unroll
      for (int r = 0; r < 4; ++r) {
        if (OUT16) {
          u16* Cz = (u16*)Cv + (size_t)blockIdx.z * (size_t)M * N;
          __builtin_nontemporal_store(f2bf(acc[m][n][r]), &Cz[(row0 + r) * N + col]);
        } else {
          float* Cz = (float*)Cv + (size_t)blockIdx.z * (size_t)M * N;
          __builtin_nontemporal_store(acc[m][n][r], &Cz[(row0 + r) * N + col]);
        }
      }
    }
}

__global__ __launch_bounds__(512, 2)
void gemm_qk(const u16* __restrict__ A, const u16* __restrict__ Bt,
             void* __restrict__ Cv, int M, int N, int K, int ntpc) {
  gemm_body<false, false, true>(A, Bt, Cv, M, N, K, ntpc);
}
__global__ __launch_bounds__(512, 2)
void gemm_pv(const u16* __restrict__ A, const u16* __restrict__ Bt,
             void* __restrict__ Cv, int M, int N, int K, int ntpc) {
  gemm_body<true, true, false>(A, Bt, Cv, M, N, K, ntpc);
}

// ============ softmax + inline threefry dropout -> bf16 P ============
__global__ __launch_bounds__(256)
void softmax_dropout(const float* __restrict__ S, u16* __restrict__ P) {
  const int tid  = threadIdx.x;
  const int lane = tid & 63;
  const int w    = tid >> 6;
  const int row  = blockIdx.x * 4 + w;   // one row per wave
  const f32x4* Sr = (const f32x4*)(S + (size_t)row * MROWS);
  f32x4 v[16];
#pragma unroll
  for (int i = 0; i < 16; ++i) v[i] = __builtin_nontemporal_load(&Sr[i * 64 + lane]);
  float m = -3.0e38f;
#pragma unroll
  for (int i = 0; i < 16; ++i)
    m = fmaxf(m, fmaxf(fmaxf(v[i][0], v[i][1]), fmaxf(v[i][2], v[i][3])));
#pragma unroll
  for (int off = 32; off > 0; off >>= 1) m = fmaxf(m, __shfl_xor(m, off, 64));
  float s = 0.0f;
#pragma unroll
  for (int i = 0; i < 16; ++i) {
    v[i][0] = __expf(v[i][0] - m); v[i][1] = __expf(v[i][1] - m);
    v[i][2] = __expf(v[i][2] - m); v[i][3] = __expf(v[i][3] - m);
    s += v[i][0] + v[i][1] + v[i][2] + v[i][3];
  }
#pragma unroll
  for (int off = 32; off > 0; off >>= 1) s += __shfl_xor(s, off, 64);
  const float inv = 2.0f / s;            // softmax normalize * 1/(1-p)
  u16* Pr = P + (size_t)row * MROWS;
#pragma unroll
  for (int i = 0; i < 16; ++i) {
    int j0 = (i * 64 + lane) * 4;
    u32 base = (u32)row * 4096u + (u32)j0;
    float e[4] = {v[i][0], v[i][1], v[i][2], v[i][3]};
    u16x4 o;
#pragma unroll
    for (int c = 0; c < 4; ++c) {
      u32 bits = threefry_bits(base + (u32)c);
      float val = (bits & 0x80000000u) ? 0.0f : e[c] * inv;   // uniform<0.5 == MSB 0
      o[c] = f2bf(val);
    }
    *(u16x4*)(Pr + j0) = o;
  }
}

// ============ split-K reduction of bf16 partials (stream in/out) ============
__global__ __launch_bounds__(256)
void reduce4(const u16* __restrict__ p, f32x4* __restrict__ out) {
  size_t i = (size_t)blockIdx.x * 256 + threadIdx.x;   // f32x4 index
  const size_t NP = (size_t)MROWS * DDIM;
  u16x4 a = __builtin_nontemporal_load((const u16x4*)(p + i*4));
  u16x4 b = __builtin_nontemporal_load((const u16x4*)(p + NP + i*4));
  u16x4 c = __builtin_nontemporal_load((const u16x4*)(p + 2*NP + i*4));
  u16x4 d = __builtin_nontemporal_load((const u16x4*)(p + 3*NP + i*4));
  f32x4 r;
  r[0] = bf2f(a[0]) + bf2f(b[0]) + bf2f(c[0]) + bf2f(d[0]);
  r[1] = bf2f(a[1]) + bf2f(b[1]) + bf2f(c[1]) + bf2f(d[1]);
  r[2] = bf2f(a[2]) + bf2f(b[2]) + bf2f(c[2]) + bf2f(d[2]);
  r[3] = bf2f(a[3]) + bf2f(b[3]) + bf2f(c[3]) + bf2f(d[3]);
  __builtin_nontemporal_store(r, &out[i]);
}

// ============ launch ============
extern "C" void kernel_launch(void* const* d_in, const int* in_sizes, int n_in,
                              void* d_out, int out_size, void* d_ws, size_t ws_size,
                              hipStream_t stream) {
  const float* x1 = (const float*)d_in[0];
  const float* x2 = (const float*)d_in[1];
  char* ws = (char*)d_ws;

  // ws layout (bytes):
  //   XA [0,16M)=Ah|Al | XB [16M,32M)=Bh|Bl | VT [32M,40M) | S [40M,104M)
  //   P (32M) overlays XA+XB after GEMM1 ; bf16 partials (32M) overlay S
  const size_t OFF_XB = 16777216;
  const size_t OFF_VT = 33554432;
  const size_t OFF_S  = 41943040;
  const size_t NEED   = 109051904;
  if (ws_size < NEED) {
    (void)hipMemsetAsync(d_out, 0x7F, (size_t)out_size * sizeof(float), stream);
    return;
  }
  u16*   XA = (u16*)(ws);
  u16*   XB = (u16*)(ws + OFF_XB);
  u16*   VT = (u16*)(ws + OFF_VT);
  float* S  = (float*)(ws + OFF_S);
  u16*   PT = (u16*)(ws + OFF_S);       // bf16 partials reuse S region
  u16*   P  = (u16*)(ws);               // reuses XA+XB region

  prep<<<3072, 256, 0, stream>>>((const float4*)x1, XA, x2, XB, VT);
  // S = (4*x1) @ x2^T via segment-dedup 3-term split, interleaved k-tile map
  gemm_qk<<<dim3(16, 16, 1), 512, 0, stream>>>(XA, XB, S, 4096, 4096, 1024, 48);
  softmax_dropout<<<1024, 256, 0, stream>>>(S, P);
  // O = P @ V: split-K x4 (K=4096, 16 tiles/chunk), bf16 partials, then reduce
  gemm_pv<<<dim3(4, 16, 4), 512, 0, stream>>>(P, VT, PT, 4096, 1024, 4096, 16);
  reduce4<<<4096, 256, 0, stream>>>(PT, (f32x4*)d_out);
}

// Round 13
// 175.454 us; speedup vs baseline: 1.1201x; 1.1201x over previous
//
#include <hip/hip_runtime.h>

typedef unsigned short u16;
typedef unsigned int   u32;
typedef __attribute__((ext_vector_type(4))) float f32x4;
typedef __attribute__((ext_vector_type(8))) short bf16x8;
typedef __attribute__((ext_vector_type(8))) unsigned short u16x8;
typedef __attribute__((ext_vector_type(4))) unsigned short u16x4;

#define MROWS 4096
#define DDIM  1024
#define SEGE  4194304   // 4096*1024 u16 elements per hi/lo segment

__device__ __forceinline__ u16 f2bf(float f) {
  u32 u = __float_as_uint(f);
  return (u16)((u + 0x7FFFu + ((u >> 16) & 1u)) >> 16);   // RNE
}
__device__ __forceinline__ float bf2f(u16 h) { return __uint_as_float(((u32)h) << 16); }

// ---------- JAX partitionable threefry2x32, key(42): bits(n) = o0^o1 ----------
__device__ __forceinline__ u32 rotl32(u32 x, int r) { return (x << r) | (x >> (32 - r)); }
__device__ __forceinline__ u32 threefry_bits(u32 n) {
  const u32 K0 = 0u, K1 = 42u, K2 = 0x1BD11BDAu ^ 0u ^ 42u;
  u32 x0 = K0;
  u32 x1 = n + K1;
#define TF4(a,b,c,d) \
  x0 += x1; x1 = rotl32(x1, a); x1 ^= x0; \
  x0 += x1; x1 = rotl32(x1, b); x1 ^= x0; \
  x0 += x1; x1 = rotl32(x1, c); x1 ^= x0; \
  x0 += x1; x1 = rotl32(x1, d); x1 ^= x0;
  TF4(13,15,26,6);  x0 += K1; x1 += K2 + 1u;
  TF4(17,29,16,24); x0 += K2; x1 += K0 + 2u;
  TF4(13,15,26,6);  x0 += K0; x1 += K1 + 3u;
  TF4(17,29,16,24); x0 += K1; x1 += K2 + 4u;
  TF4(13,15,26,6);  x0 += K2; x1 += K0 + 5u;
#undef TF4
  return x0 ^ x1;
}

// ============ merged prep: expand x1 -> Ah|Al ; x2 -> Bh|Bl + VT ============
// blocks [0,2048): expandA ; blocks [2048,3072): castB+transpose
__global__ __launch_bounds__(256)
void prep(const float4* __restrict__ x1, u16* __restrict__ XA,
          const float* __restrict__ x2, u16* __restrict__ XB, u16* __restrict__ VT) {
  __shared__ float tile[64][65];
  const int tid = threadIdx.x;
  const int b = blockIdx.x;
  if (b < 2048) {
    int t = b * 256 + tid;                       // 524288 threads, 8 floats each
    float4 v0 = x1[(size_t)t * 2], v1 = x1[(size_t)t * 2 + 1];
    float vv[8] = {v0.x*4.f, v0.y*4.f, v0.z*4.f, v0.w*4.f,
                   v1.x*4.f, v1.y*4.f, v1.z*4.f, v1.w*4.f};
    u16x8 hwv, lwv;
#pragma unroll
    for (int j = 0; j < 8; ++j) {
      u16 h = f2bf(vv[j]);
      hwv[j] = h;
      lwv[j] = f2bf(vv[j] - bf2f(h));            // Sterbenz-exact residual, RNE
    }
    *(u16x8*)(XA + (size_t)t * 8)        = hwv;
    *(u16x8*)(XA + SEGE + (size_t)t * 8) = lwv;
    return;
  }
  const int bb = b - 2048;
  const int dt = bb & 15;    // 16 D-tiles
  const int kt = bb >> 4;    // 64 K-tiles
#pragma unroll
  for (int it = 0; it < 16; ++it) {
    int lin = it * 256 + tid;
    int r = lin >> 6, c = lin & 63;
    tile[r][c] = x2[(size_t)(kt*64 + r) * DDIM + dt*64 + c];
  }
  __syncthreads();
#pragma unroll
  for (int itr = 0; itr < 2; ++itr) {
    int r  = (tid >> 3) + itr * 32;
    int c0 = (tid & 7) * 8;
    u16x8 hwv, lwv;
#pragma unroll
    for (int j = 0; j < 8; ++j) {
      float v = tile[r][c0 + j];
      u16 h = f2bf(v);
      hwv[j] = h;
      lwv[j] = f2bf(v - bf2f(h));
    }
    size_t off = (size_t)(kt*64 + r) * DDIM + dt*64 + c0;
    *(u16x8*)(XB + off)        = hwv;
    *(u16x8*)(XB + SEGE + off) = lwv;
  }
  // VT[d][k] = bf16(x2[k][d]); 16B per thread store
#pragma unroll
  for (int it = 0; it < 2; ++it) {
    int dr  = (tid >> 3) + it * 32;
    int kc0 = (tid & 7) * 8;
    u16x8 wv;
#pragma unroll
    for (int j = 0; j < 8; ++j) wv[j] = f2bf(tile[kc0 + j][dr]);
    *(u16x8*)(VT + (size_t)(dt*64 + dr) * MROWS + kt*64 + kc0) = wv;
  }
}

// ============ 256x256 pipelined 8-phase GEMM body (round-7 engine) ============
// SEG3: A = [Ah|Al], B = [Bh|Bl] panels of K=1024. INTERLEAVED k-tile map:
//   col = tau/3, seg = tau%3 ; seg 0: Ah*Bh, 1: Ah*Bl, 2: Al*Bh.
// A-slab re-staged 1 tile later, B-slab 2 tiles later -> L2-resident re-reads.
__device__ __forceinline__ void gload16(const u16* g, u16* l) {
  __builtin_amdgcn_global_load_lds(
      (const __attribute__((address_space(1))) void*)g,
      (__attribute__((address_space(3))) void*)l, 16, 0, 0);
}

#define BARRIER() do { asm volatile("" ::: "memory"); __builtin_amdgcn_s_barrier(); \
                       asm volatile("" ::: "memory"); } while (0)
#define VMCNT(N)  asm volatile("s_waitcnt vmcnt(" #N ")" ::: "memory")
#define PRIO1()   __builtin_amdgcn_s_setprio(1)
#define PRIO0()   __builtin_amdgcn_s_setprio(0)

__device__ __forceinline__ void mma_quad(f32x4 (&acc)[8][4], const bf16x8 (&aF)[4][2],
                                         const bf16x8 (&bF)[2][2], int MH, int NH) {
#pragma unroll
  for (int kx = 0; kx < 2; ++kx)
#pragma unroll
    for (int m = 0; m < 4; ++m)
#pragma unroll
      for (int n = 0; n < 2; ++n)
        acc[MH*4+m][NH*2+n] = __builtin_amdgcn_mfma_f32_16x16x32_bf16(
            aF[m][kx], bF[n][kx], acc[MH*4+m][NH*2+n], 0, 0, 0);
}

// LDS u16 layout: A(d,h) = (d*2+h)*8192 ; B(d,h) = 32768 + (d*2+h)*8192
template <bool OUT16, bool REMAP, bool SEG3>
__device__ __forceinline__ void gemm_body(const u16* __restrict__ A,
                                          const u16* __restrict__ Bt,
                                          void* __restrict__ Cv,
                                          int M, int N, int K, int ntpc) {
  __shared__ u16 smem[65536];   // 128 KiB
  const int tid = threadIdx.x;
  const int lane = tid & 63;
  const int w = tid >> 6;
  const int wr = w >> 2;          // 0..1
  const int wc = w & 3;           // 0..3
  const int fr = lane & 15;
  const int hi = lane >> 4;

  int bxi, byi;
  if (REMAP) {  // G2 (grid 4x16xZ): 2 by-rows per XCD -> L2-resident k-window
    const int id0 = blockIdx.y * gridDim.x + blockIdx.x;  // 0..63
    const int c = id0 & 7, j = id0 >> 3;
    bxi = j >> 1;
    byi = c * 2 + (j & 1);
  } else {
    bxi = blockIdx.x; byi = blockIdx.y;
  }

  const long bm = (long)byi * 256;
  const long bn = (long)bxi * 256;
  const size_t kcol0 = (size_t)blockIdx.z * ntpc * 64;

  const int srow = tid >> 3;
  const int scol = (((tid & 7) ^ (srow & 7)) << 3);
  const u16* Abase = A  + (size_t)(bm + srow) * K + kcol0 + scol;
  const u16* Bbase = Bt + (size_t)(bn + srow) * K + kcol0 + scol;

  // interleaved segment map (SEG3), uniform per block
#define SCOL(TAU) ((TAU) / 3)
#define SSEG(TAU) ((TAU) - 3 * SCOL(TAU))
#define ASEG(TAU) (SEG3 ? (Abase + (SSEG(TAU) == 2 ? (size_t)SEGE : (size_t)0) \
                                 + (size_t)SCOL(TAU)*64) \
                        : (Abase + (size_t)(TAU)*64))
#define BSEG(TAU) (SEG3 ? (Bbase + (SSEG(TAU) == 1 ? (size_t)SEGE : (size_t)0) \
                                 + (size_t)SCOL(TAU)*64) \
                        : (Bbase + (size_t)(TAU)*64))

  const int csw0 = ((hi)     ^ (fr & 7)) << 3;
  const int csw1 = ((4 + hi) ^ (fr & 7)) << 3;
  const int arow = (wr*16 + fr) * 64;
  const int brow = (wc*16 + fr) * 64;

  // RD_A2: 2 M-frags (4 ds_read_b128); RD_B: both N-frags (4)
#define RD_A2(dst, D, H, M0) do { \
    const u16* _p = smem + ((D)*2+(H))*8192 + arow + (M0)*2048; \
    dst[M0][0]   = *(const bf16x8*)(_p + csw0); \
    dst[M0][1]   = *(const bf16x8*)(_p + csw1); \
    dst[M0+1][0] = *(const bf16x8*)(_p + 2048 + csw0); \
    dst[M0+1][1] = *(const bf16x8*)(_p + 2048 + csw1); } while (0)
#define RD_B(dst, D, H) do { \
    const u16* _p = smem + 32768 + ((D)*2+(H))*8192 + brow; \
    dst[0][0] = *(const bf16x8*)(_p + csw0); \
    dst[0][1] = *(const bf16x8*)(_p + csw1); \
    dst[1][0] = *(const bf16x8*)(_p + 4096 + csw0); \
    dst[1][1] = *(const bf16x8*)(_p + 4096 + csw1); } while (0)

  f32x4 acc[8][4];
#pragma unroll
  for (int m = 0; m < 8; ++m)
#pragma unroll
    for (int n = 0; n < 4; ++n) acc[m][n] = (f32x4){0.f, 0.f, 0.f, 0.f};
  bf16x8 a0[4][2], a1[4][2], b0[2][2], b1[2][2];

#define STAGE_A(TAU,H,D) do { \
    const u16* _s = ASEG(TAU) + (size_t)(H)*128*K; \
    u16* _d = smem + ((D)*2+(H))*8192 + tid*8; \
    gload16(_s, _d); gload16(_s + (size_t)64*K, _d + 4096); } while (0)
#define STAGE_B(TAU,H,D) do { \
    const u16* _s = BSEG(TAU) + (size_t)(H)*128*K; \
    u16* _d = smem + 32768 + ((D)*2+(H))*8192 + tid*8; \
    gload16(_s, _d); gload16(_s + (size_t)64*K, _d + 4096); } while (0)

  // ---- prologue: tile0 landed; tile1's 8 loads left in flight (FIFO invariant) ----
  STAGE_A(0,0,0); STAGE_B(0,0,0);
  STAGE_B(0,1,0); STAGE_A(0,1,0);
  VMCNT(0); BARRIER();
  RD_A2(a0,0,0,0); RD_A2(a0,0,0,2); RD_B(b0,0,0);   // regs for p1
  STAGE_A(1,0,1); STAGE_B(1,0,1);                   // A0,B0(1)
  STAGE_B(1,1,1);                                   // B1(1)
  STAGE_A(1,1,1);                                   // A1(1)
  BARRIER();                                        // 8 outstanding at loop-top

  const int nt = ntpc;
  for (int T = 0; T < nt; T += 2) {
    const int t2 = (T + 2 < nt) ? T + 2 : nt - 1;   // tail: idempotent re-stage
    const int t3 = (T + 3 < nt) ? T + 3 : nt - 1;

    // p1: MFMA Q00(T)[a0,b0]; read b1(T), a1[01](T)           (8 reads)
    RD_B(b1, 0, 1); RD_A2(a1, 0, 1, 0);
    PRIO1(); mma_quad(acc, a0, b0, 0, 0); PRIO0();
    BARRIER();
    // p2: MFMA Q01(T)[a0,b1]; read a1[23](T); stage A0,B0(T+2) (4 reads)
    RD_A2(a1, 0, 1, 2);
    STAGE_A(t2, 0, 0); STAGE_B(t2, 0, 0);
    PRIO1(); mma_quad(acc, a0, b1, 0, 1); PRIO0();
    VMCNT(10); BARRIER();                 // drains A0(T+1) for p3
    // p3: MFMA Q10(T)[a1,b0]; read a0[01](T+1); stage B1(T+2)  (4 reads)
    RD_A2(a0, 1, 0, 0);
    STAGE_B(t2, 1, 0);
    PRIO1(); mma_quad(acc, a1, b0, 1, 0); PRIO0();
    VMCNT(10); BARRIER();                 // drains B0(T+1) for p4
    // p4: MFMA Q11(T)[a1,b1]; read a0[23](T+1), b0(T+1); stage A1(T+2) (8 reads)
    RD_A2(a0, 1, 0, 2); RD_B(b0, 1, 0);
    STAGE_A(t2, 1, 0);
    PRIO1(); mma_quad(acc, a1, b1, 1, 1); PRIO0();
    VMCNT(8); BARRIER();                  // drains B1(T+1), A1(T+1) for p5
    // p5: MFMA Q00(T+1)[a0,b0]; read b1(T+1), a1[01](T+1)      (8 reads)
    RD_B(b1, 1, 1); RD_A2(a1, 1, 1, 0);
    PRIO1(); mma_quad(acc, a0, b0, 0, 0); PRIO0();
    BARRIER();
    // p6: MFMA Q01(T+1)[a0,b1]; read a1[23](T+1); stage A0,B0(T+3) (4 reads)
    RD_A2(a1, 1, 1, 2);
    STAGE_A(t3, 0, 1); STAGE_B(t3, 0, 1);
    PRIO1(); mma_quad(acc, a0, b1, 0, 1); PRIO0();
    VMCNT(10); BARRIER();                 // drains A0(T+2) for p7
    // p7: MFMA Q10(T+1)[a1,b0]; read a0[01](T+2); stage B1(T+3) (4 reads)
    RD_A2(a0, 0, 0, 0);
    STAGE_B(t3, 1, 1);
    PRIO1(); mma_quad(acc, a1, b0, 1, 0); PRIO0();
    VMCNT(10); BARRIER();                 // drains B0(T+2) for p8
    // p8: MFMA Q11(T+1)[a1,b1]; read a0[23](T+2), b0(T+2); stage A1(T+3) (8 reads)
    RD_A2(a0, 0, 0, 2); RD_B(b0, 0, 0);
    STAGE_A(t3, 1, 1);
    PRIO1(); mma_quad(acc, a1, b1, 1, 1); PRIO0();
    VMCNT(8); BARRIER();                  // drains B1(T+2), A1(T+2) for next p1
  }
#undef STAGE_A
#undef STAGE_B
#undef RD_A2
#undef RD_B
#undef ASEG
#undef BSEG
#undef SCOL
#undef SSEG

  // epilogue: C/D layout col=lane&15, row=(lane>>4)*4+reg  [verified m89/m91]
#pragma unroll
  for (int m = 0; m < 8; ++m)
#pragma unroll
    for (int n = 0; n < 4; ++n) {
      size_t row0 = (size_t)(bm + m*32 + wr*16 + hi*4);
      size_t col  = (size_t)(bn + n*64 + wc*16 + fr);
#pragma unroll
      for (int r = 0; r < 4; ++r) {
        if (OUT16) {
          u16* Cz = (u16*)Cv + (size_t)blockIdx.z * (size_t)M * N;
          Cz[(row0 + r) * N + col] = f2bf(acc[m][n][r]);
        } else {
          float* Cz = (float*)Cv + (size_t)blockIdx.z * (size_t)M * N;
          Cz[(row0 + r) * N + col] = acc[m][n][r];
        }
      }
    }
}

__global__ __launch_bounds__(512, 2)
void gemm_qk(const u16* __restrict__ A, const u16* __restrict__ Bt,
             void* __restrict__ Cv, int M, int N, int K, int ntpc) {
  gemm_body<false, false, true>(A, Bt, Cv, M, N, K, ntpc);
}
__global__ __launch_bounds__(512, 2)
void gemm_pv(const u16* __restrict__ A, const u16* __restrict__ Bt,
             void* __restrict__ Cv, int M, int N, int K, int ntpc) {
  gemm_body<true, true, false>(A, Bt, Cv, M, N, K, ntpc);
}

// ============ softmax + inline threefry dropout -> bf16 P ============
__global__ __launch_bounds__(256)
void softmax_dropout(const float* __restrict__ S, u16* __restrict__ P) {
  const int tid  = threadIdx.x;
  const int lane = tid & 63;
  const int w    = tid >> 6;
  const int row  = blockIdx.x * 4 + w;   // one row per wave
  const float4* Sr = (const float4*)(S + (size_t)row * MROWS);
  float4 v[16];
#pragma unroll
  for (int i = 0; i < 16; ++i) v[i] = Sr[i * 64 + lane];
  float m = -3.0e38f;
#pragma unroll
  for (int i = 0; i < 16; ++i)
    m = fmaxf(m, fmaxf(fmaxf(v[i].x, v[i].y), fmaxf(v[i].z, v[i].w)));
#pragma unroll
  for (int off = 32; off > 0; off >>= 1) m = fmaxf(m, __shfl_xor(m, off, 64));
  float s = 0.0f;
#pragma unroll
  for (int i = 0; i < 16; ++i) {
    v[i].x = __expf(v[i].x - m); v[i].y = __expf(v[i].y - m);
    v[i].z = __expf(v[i].z - m); v[i].w = __expf(v[i].w - m);
    s += v[i].x + v[i].y + v[i].z + v[i].w;
  }
#pragma unroll
  for (int off = 32; off > 0; off >>= 1) s += __shfl_xor(s, off, 64);
  const float inv = 2.0f / s;            // softmax normalize * 1/(1-p)
  u16* Pr = P + (size_t)row * MROWS;
#pragma unroll
  for (int i = 0; i < 16; ++i) {
    int j0 = (i * 64 + lane) * 4;
    u32 base = (u32)row * 4096u + (u32)j0;
    float e[4] = {v[i].x, v[i].y, v[i].z, v[i].w};
    u16x4 o;
#pragma unroll
    for (int c = 0; c < 4; ++c) {
      u32 bits = threefry_bits(base + (u32)c);
      float val = (bits & 0x80000000u) ? 0.0f : e[c] * inv;   // uniform<0.5 == MSB 0
      o[c] = f2bf(val);
    }
    *(u16x4*)(Pr + j0) = o;
  }
}

// ============ split-K reduction of bf16 partials ============
__global__ __launch_bounds__(256)
void reduce4(const u16* __restrict__ p, float4* __restrict__ out) {
  size_t i = (size_t)blockIdx.x * 256 + threadIdx.x;   // float4 index
  const size_t NP = (size_t)MROWS * DDIM;
  u16x4 a = *(const u16x4*)(p + i*4);
  u16x4 b = *(const u16x4*)(p + NP + i*4);
  u16x4 c = *(const u16x4*)(p + 2*NP + i*4);
  u16x4 d = *(const u16x4*)(p + 3*NP + i*4);
  float4 r;
  r.x = bf2f(a[0]) + bf2f(b[0]) + bf2f(c[0]) + bf2f(d[0]);
  r.y = bf2f(a[1]) + bf2f(b[1]) + bf2f(c[1]) + bf2f(d[1]);
  r.z = bf2f(a[2]) + bf2f(b[2]) + bf2f(c[2]) + bf2f(d[2]);
  r.w = bf2f(a[3]) + bf2f(b[3]) + bf2f(c[3]) + bf2f(d[3]);
  out[i] = r;
}

// ============ launch ============
extern "C" void kernel_launch(void* const* d_in, const int* in_sizes, int n_in,
                              void* d_out, int out_size, void* d_ws, size_t ws_size,
                              hipStream_t stream) {
  const float* x1 = (const float*)d_in[0];
  const float* x2 = (const float*)d_in[1];
  char* ws = (char*)d_ws;

  // ws layout (bytes):
  //   XA [0,16M)=Ah|Al | XB [16M,32M)=Bh|Bl | VT [32M,40M) | S [40M,104M)
  //   P (32M) overlays XA+XB after GEMM1 ; bf16 partials (32M) overlay S
  const size_t OFF_XB = 16777216;
  const size_t OFF_VT = 33554432;
  const size_t OFF_S  = 41943040;
  const size_t NEED   = 109051904;
  if (ws_size < NEED) {
    (void)hipMemsetAsync(d_out, 0x7F, (size_t)out_size * sizeof(float), stream);
    return;
  }
  u16*   XA = (u16*)(ws);
  u16*   XB = (u16*)(ws + OFF_XB);
  u16*   VT = (u16*)(ws + OFF_VT);
  float* S  = (float*)(ws + OFF_S);
  u16*   PT = (u16*)(ws + OFF_S);       // bf16 partials reuse S region
  u16*   P  = (u16*)(ws);               // reuses XA+XB region

  prep<<<3072, 256, 0, stream>>>((const float4*)x1, XA, x2, XB, VT);
  // S = (4*x1) @ x2^T via segment-dedup 3-term split, interleaved k-tile map
  gemm_qk<<<dim3(16, 16, 1), 512, 0, stream>>>(XA, XB, S, 4096, 4096, 1024, 48);
  softmax_dropout<<<1024, 256, 0, stream>>>(S, P);
  // O = P @ V: split-K x4 (K=4096, 16 tiles/chunk), bf16 partials, then reduce
  gemm_pv<<<dim3(4, 16, 4), 512, 0, stream>>>(P, VT, PT, 4096, 1024, 4096, 16);
  reduce4<<<4096, 256, 0, stream>>>(PT, (float4*)d_out);
}